// Round 7
// baseline (588.512 us; speedup 1.0000x reference)
//
#include <hip/hip_runtime.h>

#define G    128          // 4*HID
#define HID  32
#define EMB  16
#define BB   256
#define TT   2048
#define VOC  5000

typedef float v2f __attribute__((ext_vector_type(2)));
typedef float v4f __attribute__((ext_vector_type(4)));
typedef __attribute__((ext_vector_type(8))) short short8;   // 8 bf16 (4 VGPRs)
typedef __attribute__((ext_vector_type(4))) float f32x4;    // MFMA C/D frag

__device__ __forceinline__ float bf2f(unsigned short u) {
    return __uint_as_float(((unsigned)u) << 16);
}
__device__ __forceinline__ unsigned short f2bf(float f) {
    unsigned x = __float_as_uint(f);
    return (unsigned short)((x + 0x7FFFu + ((x >> 16) & 1u)) >> 16);  // RNE
}
__device__ __forceinline__ float sigm(float x) {
    const float e = __expf(-x);
    return __builtin_amdgcn_rcpf(1.f + e);
}
__device__ __forceinline__ float tanh_f(float x) {
    const float e = __expf(-2.f * x);
    return (1.f - e) * __builtin_amdgcn_rcpf(1.f + e);
}
__device__ __forceinline__ float rdlf(float v, int k) {
    return __int_as_float(__builtin_amdgcn_readlane(__float_as_int(v), k));
}
__device__ __forceinline__ int rdli(int v, int k) {
    return __builtin_amdgcn_readlane(v, k);
}
// DPP quad-perm lane exchange (pure VALU; no LDS pipe)
template <int CTRL>
__device__ __forceinline__ unsigned dppq_u(unsigned v) {
    return (unsigned)__builtin_amdgcn_update_dpp(0, (int)v, CTRL, 0xF, 0xF, true);
}
#define DPP_XOR1 0xB1   // quad_perm [1,0,3,2]

// ---------------------------------------------------------------------------
// Dtype detector (flag=1 -> fp32 buffers, flag=0 -> bf16 buffers). Proven.
// ---------------------------------------------------------------------------
__global__ void detect_kernel(const unsigned int* __restrict__ bias_w,
                              int* __restrict__ flag) {
    if (threadIdx.x == 0 && blockIdx.x == 0) {
        bool evens_zero = true, anybig = false;
        for (int i = 0; i < 64; ++i) {
            const unsigned u  = bias_w[i];
            const unsigned lo = u & 0xFFFFu;
            const float vlo = __uint_as_float(lo << 16);
            const float vhi = __uint_as_float(u & 0xFFFF0000u);
            if (lo != 0u) evens_zero = false;
            if (!(fabsf(vlo) < 1e6f) || !(fabsf(vhi) < 1e6f)) anybig = true;
        }
        *flag = (evens_zero || anybig) ? 1 : 0;
    }
}

// ---------------------------------------------------------------------------
// Token z-table, gate-grouped: ZK[v][4u+g] = z_x gate g of unit u
// (g: 0=i,1=f,2=g,3=o; original Wk/bias column = 32g + u).
// Thread l computes entries 2l, 2l+1 of row v.
// ---------------------------------------------------------------------------
__global__ __launch_bounds__(64) void zk_kernel(
    const void* __restrict__ emb, const void* __restrict__ Wk,
    const void* __restrict__ bias, float* __restrict__ ZK,
    const int* __restrict__ flag)
{
    const int l = threadIdx.x;
    const int v = blockIdx.x;
    const bool f32 = flag[0] != 0;
    const int e0 = 2 * l, e1 = 2 * l + 1;
    const int c0 = 32 * (e0 & 3) + (e0 >> 2);
    const int c1 = 32 * (e1 & 3) + (e1 >> 2);

    float x[EMB], wa[EMB], wb[EMB], ba, bb;
    if (f32) {
        const float* E = (const float*)emb + (size_t)v * EMB;
        const float* W = (const float*)Wk;
        const float* B = (const float*)bias;
#pragma unroll
        for (int e = 0; e < EMB; ++e) {
            x[e]  = E[e];
            wa[e] = W[e * G + c0];
            wb[e] = W[e * G + c1];
        }
        ba = B[c0]; bb = B[c1];
    } else {
        const unsigned short* E = (const unsigned short*)emb + (size_t)v * EMB;
        const unsigned short* W = (const unsigned short*)Wk;
        const unsigned short* B = (const unsigned short*)bias;
#pragma unroll
        for (int e = 0; e < EMB; ++e) {
            x[e]  = bf2f(E[e]);
            wa[e] = bf2f(W[e * G + c0]);
            wb[e] = bf2f(W[e * G + c1]);
        }
        ba = bf2f(B[c0]); bb = bf2f(B[c1]);
    }
    float za = ba, zb = bb;
#pragma unroll
    for (int e = 0; e < EMB; ++e) {
        za = fmaf(x[e], wa[e], za);
        zb = fmaf(x[e], wb[e], zb);
    }
    v2f r; r.x = za; r.y = zb;
    *(v2f*)(ZK + (size_t)v * G + e0) = r;
}

// ---------------------------------------------------------------------------
// Scan, 2 sequences per wave: lane l -> seq (l>>5), unit j = l&31.
// A-frag rows 0-7 = h_A, 8-15 = h_B (shared 8 MFMAs). B-frags permuted so
// lane l's 4 gates arrive locally: r2=(l>>4)&1 picks d0-3 vs d4-7.
// Per step: DPP xor1 pair-pack, 4x ds_bpermute (one DS hop), 8 MFMAs,
// all-4-gates-per-lane math, ballot mask, 1 store/lane.
// ---------------------------------------------------------------------------
template <bool F32OUT>
__device__ void scan2_loop(const int* __restrict__ trowme,
                           const float* __restrict__ ZK,
                           char* __restrict__ orowc,   // my seq's output base
                           const short8 (&Bf)[8], int lane)
{
    const int  j    = lane & 31;
    const bool r2   = (lane >> 4) & 1;          // unit group within seq
    const bool odd  = lane & 1;                 // unit parity
    const int  zoff = 4 * j;                    // float offset into ZK row
    // bpermute byte-addr: srclane = 32*seq(m) + 8*oct + 2q,  m=lane&15
    int badr[4];
#pragma unroll
    for (int q = 0; q < 4; ++q)
        badr[q] = 4 * (32 * ((lane >> 3) & 1) + 8 * (lane >> 4) + 2 * q);

    const f32x4 zc = {0.f, 0.f, 0.f, 0.f};
    float h = 0.f, c = 0.f;

    int vt0 = trowme[j];            // my seq, tokens of current 32-chunk
    int vt1 = trowme[32 + j];       // next chunk

    v4f pz[4];
#pragma unroll
    for (int d = 0; d < 4; ++d) {
        const int ta = rdli(vt0, d), tb = rdli(vt0, 32 + d);
        const int tk = (lane & 32) ? tb : ta;
        pz[d] = *(const v4f*)(ZK + (size_t)tk * G + zoff);
    }

    for (int cc = 0; cc < TT / 32; ++cc) {
        const unsigned long long mw = __ballot(vt0 != 0);
        for (int qq = 0; qq < 8; ++qq) {
#pragma unroll
            for (int u = 0; u < 4; ++u) {
                const int q = qq * 4 + u;
                const int t = cc * 32 + q;
                const v4f z = pz[u];
                {   // prefetch z for step q+4 of my seq
                    const int idx = q + 4;
                    int ta, tb;
                    if (idx < 32) { ta = rdli(vt0, idx); tb = rdli(vt0, idx + 32); }
                    else          { ta = rdli(vt1, idx - 32); tb = rdli(vt1, idx); }
                    const int tk = (lane & 32) ? tb : ta;
                    pz[u] = *(const v4f*)(ZK + (size_t)tk * G + zoff);
                }

                // ---- A-frag: bf16(h) pairs via DPP xor1, one bpermute hop ----
                const unsigned rh  = __float_as_uint(h) + 0x8000u; // round-half-up
                const unsigned prt = dppq_u<DPP_XOR1>(rh);         // partner unit j^1
                const unsigned plo = odd ? prt : rh;               // even-unit half
                const unsigned phi = odd ? rh : prt;               // odd-unit half
                const unsigned pair = __builtin_amdgcn_perm(phi, plo, 0x07060302u);
                union { unsigned u4[4]; short8 s8; } au;
#pragma unroll
                for (int q2 = 0; q2 < 4; ++q2)
                    au.u4[q2] = (unsigned)__builtin_amdgcn_ds_bpermute(badr[q2], (int)pair);
                const short8 Af = au.s8;

                // ---- 8 MFMAs: both seqs, all 128 gate-cols each ----
                f32x4 d0 = __builtin_amdgcn_mfma_f32_16x16x32_bf16(Af, Bf[0], zc, 0, 0, 0);
                f32x4 d1 = __builtin_amdgcn_mfma_f32_16x16x32_bf16(Af, Bf[1], zc, 0, 0, 0);
                f32x4 d2 = __builtin_amdgcn_mfma_f32_16x16x32_bf16(Af, Bf[2], zc, 0, 0, 0);
                f32x4 d3 = __builtin_amdgcn_mfma_f32_16x16x32_bf16(Af, Bf[3], zc, 0, 0, 0);
                f32x4 d4 = __builtin_amdgcn_mfma_f32_16x16x32_bf16(Af, Bf[4], zc, 0, 0, 0);
                f32x4 d5 = __builtin_amdgcn_mfma_f32_16x16x32_bf16(Af, Bf[5], zc, 0, 0, 0);
                f32x4 d6 = __builtin_amdgcn_mfma_f32_16x16x32_bf16(Af, Bf[6], zc, 0, 0, 0);
                f32x4 d7 = __builtin_amdgcn_mfma_f32_16x16x32_bf16(Af, Bf[7], zc, 0, 0, 0);

                // reg0 row = 4*(lane>>4) -> my seq's broadcast row
                const float zi = z.x + (r2 ? d4.x : d0.x);
                const float zf = z.y + (r2 ? d5.x : d1.x);
                const float zg = z.z + (r2 ? d6.x : d2.x);
                const float zo = z.w + (r2 ? d7.x : d3.x);

                const float iV = sigm(zi);
                const float fV = sigm(zf);
                const float s2 = sigm(2.f * zg);
                const float gV = fmaf(s2, 2.f, -1.f);
                const float oV = sigm(zo);
                const float cN = fmaf(fV, c, iV * gV);
                const float hN = oV * tanh_f(cN);

                const int  sh = q + (lane & 32);
                const bool m  = (mw >> sh) & 1ull;
                c = m ? cN : c;
                h = m ? hN : h;

                const int oi = t * HID + j;
                if (F32OUT) __builtin_nontemporal_store(h, (float*)orowc + oi);
                else        __builtin_nontemporal_store(f2bf(h), (unsigned short*)orowc + oi);
            }
        }
        vt0 = vt1;
        if (cc + 2 < TT / 32) vt1 = trowme[(cc + 2) * 32 + j];
        // else: vt1 stale = valid earlier tokens -> prefetch rows harmless
    }
}

__global__ __launch_bounds__(64) void scan_zk2_kernel(
    const int* __restrict__ tokens, const float* __restrict__ ZK,
    const void* __restrict__ Wr, const void* __restrict__ bias,
    void* __restrict__ out, const int* __restrict__ flag)
{
    const int lane = threadIdx.x, b = blockIdx.x;
    const bool f32 = flag[0] != 0;
    const int seq  = 2 * b + (lane >> 5);

    // B-frags: MFMA p<4 -> gate p of units 0-15 (Wr col 32p+n);
    //          p>=4 -> gate p-4 of units 16-31 (Wr col 32(p-4)+16+n).
    // Lane holds B[k=(lane>>4)*8+jj][n=lane&15].
    short8 Bf[8];
    const int n  = lane & 15;
    const int k0 = (lane >> 4) * 8;
#pragma unroll
    for (int p = 0; p < 8; ++p) {
        const int col = (p < 4) ? (32 * p + n) : (32 * (p - 4) + 16 + n);
        short el[8];
        if (f32) {
            const float* W = (const float*)Wr;
#pragma unroll
            for (int jj = 0; jj < 8; ++jj) el[jj] = (short)f2bf(W[(k0 + jj) * G + col]);
        } else {
            const unsigned short* W = (const unsigned short*)Wr;
#pragma unroll
            for (int jj = 0; jj < 8; ++jj) el[jj] = (short)W[(k0 + jj) * G + col];
        }
        short8 s;
#pragma unroll
        for (int jj = 0; jj < 8; ++jj) s[jj] = el[jj];
        Bf[p] = s;
    }

    const int* trowme = tokens + (size_t)seq * TT;
    if (f32) scan2_loop<true >(trowme, ZK, (char*)out + (size_t)seq * TT * HID * 4, Bf, lane);
    else     scan2_loop<false>(trowme, ZK, (char*)out + (size_t)seq * TT * HID * 2, Bf, lane);
}

// ---------------------------------------------------------------------------
// Fallback (workspace too small): proven R2/R3 fused kernel.
// ---------------------------------------------------------------------------
template <bool F32>
__device__ __forceinline__ void row_load(const void* emb, int tok, uint4* r) {
    if (F32) { const uint4* p = (const uint4*)((const float*)emb + (size_t)tok*EMB);
               r[0]=p[0]; r[1]=p[1]; r[2]=p[2]; r[3]=p[3]; }
    else     { const uint4* p = (const uint4*)((const unsigned short*)emb + (size_t)tok*EMB);
               r[0]=p[0]; r[1]=p[1]; }
}
template <bool F32>
__device__ __forceinline__ void row_unpack(const uint4* r, float* x) {
    if (F32) {
        const unsigned w[16] = {r[0].x,r[0].y,r[0].z,r[0].w, r[1].x,r[1].y,r[1].z,r[1].w,
                                r[2].x,r[2].y,r[2].z,r[2].w, r[3].x,r[3].y,r[3].z,r[3].w};
#pragma unroll
        for (int e = 0; e < 16; ++e) x[e] = __uint_as_float(w[e]);
    } else {
        const unsigned w[8] = {r[0].x,r[0].y,r[0].z,r[0].w, r[1].x,r[1].y,r[1].z,r[1].w};
#pragma unroll
        for (int q = 0; q < 8; ++q) {
            x[2*q]   = __uint_as_float(w[q] << 16);
            x[2*q+1] = __uint_as_float(w[q] & 0xFFFF0000u);
        }
    }
}

template <bool F32>
__device__ __forceinline__ void scan_fused_loop(
    const int* __restrict__ trow, const void* __restrict__ emb, void* orow,
    const float (&wka)[EMB], const float (&wkb)[EMB],
    const float (&wra)[HID], const float (&wrb)[HID],
    float za0, float zb0, const int* tl, int lane)
{
    const bool  lo  = lane < HID;
    const float zsc = lo ? 2.f : 1.f, gm = lo ? 2.f : 1.f, ga = lo ? -1.f : 0.f;
    float h = 0.f, c = 0.f;
    uint4 praw[2][4];
    row_load<F32>(emb, trow[0], praw[0]);
    row_load<F32>(emb, trow[1], praw[1]);

    for (int tt = 0; tt < TT; tt += 2) {
#pragma unroll
        for (int u = 0; u < 2; ++u) {
            const int t = tt + u;
            float x[EMB];
            row_unpack<F32>(praw[u], x);
            int tn = t + 2; tn = tn > TT - 1 ? TT - 1 : tn;
            row_load<F32>(emb, tl[tn], praw[u]);
            float za = za0, zb = zb0;
#pragma unroll
            for (int e = 0; e < EMB; ++e) { za = fmaf(x[e], wka[e], za); zb = fmaf(x[e], wkb[e], zb); }
#pragma unroll
            for (int k = 0; k < HID; ++k) {
                const float hk = rdlf(h, k);
                za = fmaf(hk, wra[k], za);
                zb = fmaf(hk, wrb[k], zb);
            }
            const float a1 = sigm(za);
            const float s2 = sigm(zb * zsc);
            const float a2 = fmaf(s2, gm, ga);
            const float x1 = __shfl_xor(a1, 32);
            const float x2 = __shfl_xor(a2, 32);
            const float iV = lo ? a1 : x1, fV = lo ? x1 : a1;
            const float gV = lo ? a2 : x2, oV = lo ? x2 : a2;
            const float cN = fmaf(fV, c, iV * gV);
            const float hN = oV * tanh_f(cN);
            const bool  m  = tl[t] != 0;
            c = m ? cN : c;
            h = m ? hN : h;
            const int oi = t * HID + (lane & (HID - 1));
            if (F32) ((float*)orow)[oi] = h;
            else     ((unsigned short*)orow)[oi] = f2bf(h);
        }
    }
}

__global__ __launch_bounds__(64) void scan_fused_kernel(
    const int* __restrict__ tokens, const void* __restrict__ emb,
    const void* __restrict__ Wk, const void* __restrict__ Wr,
    const void* __restrict__ bias, void* __restrict__ out,
    const int* __restrict__ flag, int defmode)
{
    __shared__ int tl[TT];
    const int lane = threadIdx.x, b = blockIdx.x;
    const bool f32 = flag ? (flag[0] != 0) : (defmode != 0);
    const int* trow = tokens + (size_t)b * TT;
    for (int t = lane; t < TT; t += 64) tl[t] = trow[t];

    float wka[EMB], wkb[EMB], wra[HID], wrb[HID], za0, zb0;
    if (f32) {
        const float* WK = (const float*)Wk; const float* WR = (const float*)Wr;
        const float* B  = (const float*)bias;
#pragma unroll
        for (int e = 0; e < EMB; ++e) { wka[e] = WK[e*G + lane]; wkb[e] = WK[e*G + lane + 64]; }
#pragma unroll
        for (int k = 0; k < HID; ++k) { wra[k] = WR[k*G + lane]; wrb[k] = WR[k*G + lane + 64]; }
        za0 = B[lane]; zb0 = B[lane + 64];
    } else {
        const unsigned short* WK = (const unsigned short*)Wk;
        const unsigned short* WR = (const unsigned short*)Wr;
        const unsigned short* B  = (const unsigned short*)bias;
#pragma unroll
        for (int e = 0; e < EMB; ++e) { wka[e] = bf2f(WK[e*G + lane]); wkb[e] = bf2f(WK[e*G + lane + 64]); }
#pragma unroll
        for (int k = 0; k < HID; ++k) { wra[k] = bf2f(WR[k*G + lane]); wrb[k] = bf2f(WR[k*G + lane + 64]); }
        za0 = bf2f(B[lane]); zb0 = bf2f(B[lane + 64]);
    }
    __syncthreads();

    if (f32) scan_fused_loop<true >(trow, emb, (char*)out + (size_t)b*TT*HID*4,
                                    wka, wkb, wra, wrb, za0, zb0, tl, lane);
    else     scan_fused_loop<false>(trow, emb, (char*)out + (size_t)b*TT*HID*2,
                                    wka, wkb, wra, wrb, za0, zb0, tl, lane);
}

// ---------------------------------------------------------------------------
extern "C" void kernel_launch(void* const* d_in, const int* in_sizes, int n_in,
                              void* d_out, int out_size, void* d_ws, size_t ws_size,
                              hipStream_t stream) {
    const int*  tokens = (const int*)d_in[0];
    const void* emb    = d_in[1];
    const void* Wk     = d_in[2];
    const void* Wr     = d_in[3];
    const void* bias   = d_in[4];

    const size_t zk_off   = 256;
    const size_t zk_bytes = (size_t)VOC * G * sizeof(float);   // 2.56 MB

    if (ws_size >= zk_off + zk_bytes) {
        int*   flag = (int*)d_ws;
        float* ZK   = (float*)((char*)d_ws + zk_off);
        detect_kernel<<<1, 64, 0, stream>>>((const unsigned int*)bias, flag);
        zk_kernel<<<VOC, 64, 0, stream>>>(emb, Wk, bias, ZK, flag);
        scan_zk2_kernel<<<BB / 2, 64, 0, stream>>>(tokens, ZK, Wr, bias, d_out, flag);
    } else if (ws_size >= 16) {
        int* flag = (int*)d_ws;
        detect_kernel<<<1, 64, 0, stream>>>((const unsigned int*)bias, flag);
        scan_fused_kernel<<<BB, 64, 0, stream>>>(tokens, emb, Wk, Wr, bias, d_out, flag, 1);
    } else {
        scan_fused_kernel<<<BB, 64, 0, stream>>>(tokens, emb, Wk, Wr, bias, d_out, nullptr, 1);
    }
}